// Round 2
// baseline (830.167 us; speedup 1.0000x reference)
//
#include <hip/hip_runtime.h>
#include <hip/hip_bf16.h>

// CTC loss forward: T=512, B=32, V=8000, L=100, S=2L+1=201, BLANK=0.
// Plan:
//  K1: per (t,b) row: stream 8000 floats HBM->LDS once, compute log-sum-exp,
//      gather 101 needed classes (blank + labels), store lp*log2e to ws [B][T][104].
//  K2: per sample (32 blocks x 1 wave): blocked-state alpha recursion, 4 states/lane,
//      one shfl_up per step, lp chunks double-buffered in LDS (32 steps/chunk).
//  K3: sum 32 partials -> loss scalar.

#define LOG2E 1.4426950408889634f
#define LN2   0.69314718055994530942f
#define NEGS  (-1.4426950408889634e30f)   /* -1e30 scaled by log2e */

__device__ __forceinline__ float lae2(float a, float b) {
    float m = fmaxf(a, b);
    float d = fminf(a, b) - m;
    return m + log2f(1.0f + exp2f(d));
}
__device__ __forceinline__ float lae3(float a, float b, float c) {
    float m = fmaxf(fmaxf(a, b), c);
    float s = exp2f(a - m) + exp2f(b - m) + exp2f(c - m);
    return m + log2f(s);
}

// ---------------- Kernel 1: row log-sum-exp + gather ----------------
__global__ __launch_bounds__(256)
void ctc_rowlse(const float* __restrict__ acts, const int* __restrict__ targets,
                float* __restrict__ lp) {
    const int B = 32, V = 8000, L = 100, RS = 104;
    const int bid = blockIdx.x;
    const int t = bid >> 5, b = bid & 31;
    const int tid = threadIdx.x;

    __shared__ float4 rowv[2000];          // 32000 B: the full row
    __shared__ float red[8];

    const float4* g = (const float4*)(acts + ((size_t)t * B + b) * V);

    float m = -3.0e38f;
    for (int i = tid; i < 2000; i += 256) {
        float4 v = g[i];
        rowv[i] = v;
        m = fmaxf(fmaxf(fmaxf(m, v.x), fmaxf(v.y, v.z)), v.w);
    }
    #pragma unroll
    for (int o = 32; o > 0; o >>= 1) m = fmaxf(m, __shfl_xor(m, o));
    if ((tid & 63) == 0) red[tid >> 6] = m;
    __syncthreads();
    m = fmaxf(fmaxf(red[0], red[1]), fmaxf(red[2], red[3]));

    float s = 0.f;
    for (int i = tid; i < 2000; i += 256) {
        float4 v = rowv[i];
        s += exp2f((v.x - m) * LOG2E) + exp2f((v.y - m) * LOG2E)
           + exp2f((v.z - m) * LOG2E) + exp2f((v.w - m) * LOG2E);
    }
    #pragma unroll
    for (int o = 32; o > 0; o >>= 1) s += __shfl_xor(s, o);
    if ((tid & 63) == 0) red[4 + (tid >> 6)] = s;
    __syncthreads();
    s = red[4] + red[5] + red[6] + red[7];

    const float base = m * LOG2E + log2f(s);   // log2(sum exp), incl. max

    if (tid < 101) {
        int cls = (tid == 0) ? 0 : targets[b * L + tid - 1];
        const float* rowf = (const float*)rowv;
        // lp2 = (x - logsumexp) * log2e, stored in log2 domain
        lp[((size_t)b * 512 + t) * RS + tid] = rowf[cls] * LOG2E - base;
    }
}

// ---------------- Kernel 2: alpha recursion (1 wave / sample) ----------------
__global__ __launch_bounds__(64)
void ctc_alpha(const float* __restrict__ lp, const int* __restrict__ targets,
               const int* __restrict__ act_lens, const int* __restrict__ label_lens,
               float* __restrict__ partials) {
    const int T = 512, L = 100, RS = 104, CH = 32;
    const int b = blockIdx.x;
    const int l = threadIdx.x;

    __shared__ float4 buf[2][CH * RS / 4];   // 2 x 3328 floats = 26.6 KB
    __shared__ float afin[256];

    const int* tg = targets + b * L;

    // lane l owns states s0..s0+3; even states = blank (k=0), odd = labels
    const int s0 = 4 * l;
    const int i1 = 2 * l;        // label index of state s0+1
    const int i3 = 2 * l + 1;    // label index of state s0+3
    const bool v1 = (s0 + 1) <= 200;
    const bool v3 = (s0 + 3) <= 200;
    const int q1  = (i1 < L) ? i1 : (L - 1);
    const int q1m = (i1 >= 1) ? ((i1 - 1 < L) ? i1 - 1 : (L - 1)) : 0;
    const int q3  = (i3 < L) ? i3 : (L - 1);
    const int c1 = tg[q1], c1m = tg[q1m], c3 = tg[q3];
    const bool can1 = (i1 == 0) || (c1 != c1m);
    const bool can3 = (c3 != c1);
    const int k1 = v1 ? (1 + i1) : 0;
    const int k3 = v3 ? (1 + i3) : 0;
    const int act_len = act_lens[b];

    const float4* gsrc = (const float4*)(lp + (size_t)b * T * RS);

    // stage chunk 0
    float4 stg[13];
    #pragma unroll
    for (int i = 0; i < 13; ++i) stg[i] = gsrc[i * 64 + l];
    #pragma unroll
    for (int i = 0; i < 13; ++i) buf[0][i * 64 + l] = stg[i];
    __syncthreads();

    float a0 = NEGS, a1 = NEGS, a2 = NEGS, a3 = NEGS;
    {
        const float* row0 = (const float*)&buf[0][0];
        if (l == 0) { a0 = row0[0]; a1 = row0[1]; }
    }

    int gt = 1;
    for (int c = 0; c < 16; ++c) {
        if (c < 15) {   // issue next-chunk loads early (hide under compute)
            const float4* gn = gsrc + (size_t)(c + 1) * (CH * RS / 4);
            #pragma unroll
            for (int i = 0; i < 13; ++i) stg[i] = gn[i * 64 + l];
        }
        const float* rowbase = (const float*)&buf[c & 1][0];
        const int tstart = (c == 0) ? 1 : 0;
        for (int tt = tstart; tt < CH; ++tt, ++gt) {
            const float* row = rowbase + tt * RS;
            float lpB = row[0];
            float lq1 = v1 ? row[k1] : NEGS;
            float lq3 = v3 ? row[k3] : NEGS;
            float p3 = __shfl_up(a3, 1);           // alpha[s0-1] from lane l-1
            if (l == 0) p3 = NEGS;
            float na0 = lae2(a0, p3) + lpB;
            float na1 = lae3(a1, a0, can1 ? p3 : NEGS) + lq1;
            float na2 = lae2(a2, a1) + lpB;
            float na3 = lae3(a3, a2, can3 ? a1 : NEGS) + lq3;
            if (gt < act_len) { a0 = na0; a1 = na1; a2 = na2; a3 = na3; }
        }
        if (c < 15) {   // commit staged chunk, then make visible
            float4* dst = &buf[(c + 1) & 1][0];
            #pragma unroll
            for (int i = 0; i < 13; ++i) dst[i * 64 + l] = stg[i];
            __syncthreads();
        }
    }

    afin[4 * l + 0] = a0; afin[4 * l + 1] = a1;
    afin[4 * l + 2] = a2; afin[4 * l + 3] = a3;
    __syncthreads();
    if (l == 0) {
        int Lb = label_lens[b];
        int sl = 2 * Lb;
        float ll = lae2(afin[sl], afin[sl - 1]);   // log2 domain
        partials[b] = -ll * LN2;                   // back to natural log
    }
}

// ---------------- Kernel 3: final mean ----------------
__global__ __launch_bounds__(64)
void ctc_final(const float* __restrict__ partials, float* __restrict__ out) {
    int tid = threadIdx.x;
    float v = (tid < 32) ? partials[tid] : 0.f;
    #pragma unroll
    for (int o = 32; o > 0; o >>= 1) v += __shfl_xor(v, o);
    if (tid == 0) out[0] = v * (1.0f / 32.0f);
}

extern "C" void kernel_launch(void* const* d_in, const int* in_sizes, int n_in,
                              void* d_out, int out_size, void* d_ws, size_t ws_size,
                              hipStream_t stream) {
    const float* acts      = (const float*)d_in[0];
    const int*   targets   = (const int*)d_in[1];
    const int*   act_lens  = (const int*)d_in[2];
    const int*   label_lens= (const int*)d_in[3];

    float* lp       = (float*)d_ws;                                    // [32][512][104]
    float* partials = (float*)((char*)d_ws + (size_t)32 * 512 * 104 * sizeof(float));

    ctc_rowlse<<<16384, 256, 0, stream>>>(acts, targets, lp);
    ctc_alpha <<<32, 64, 0, stream>>>(lp, targets, act_lens, label_lens, partials);
    ctc_final <<<1, 64, 0, stream>>>(partials, (float*)d_out);
}

// Round 3
// 824.106 us; speedup vs baseline: 1.0074x; 1.0074x over previous
//
#include <hip/hip_runtime.h>
#include <hip/hip_bf16.h>

// CTC loss forward: T=512, B=32, V=8000, L=100, S=2L+1=201, BLANK=0.
//  K1 ctc_rowlse: per (t,b) row (16384 blocks x 256 thr): stream 8000 floats
//     HBM->registers (8 float4/thread), max-reduce + exp2-sum from regs
//     (no LDS row buffer -> 8 blocks/CU, 32 waves/CU), gather 101 classes
//     straight from global (L2-hot), store log2-domain logprobs to ws [B][T][104].
//  K2 ctc_alpha: per sample (32 blocks x 1 wave): blocked-state alpha recursion,
//     4 states/lane, one shfl_up/step, lp double-buffered in LDS, 32 steps/chunk.
//  K3 ctc_final: mean of 32 partials.

#define LOG2E 1.4426950408889634f
#define LN2   0.69314718055994530942f
#define NEGS  (-1.4426950408889634e30f)   /* -1e30 scaled by log2e */

__device__ __forceinline__ float lae2(float a, float b) {
    float m = fmaxf(a, b);
    float d = fminf(a, b) - m;
    return m + log2f(1.0f + exp2f(d));
}
__device__ __forceinline__ float lae3(float a, float b, float c) {
    float m = fmaxf(fmaxf(a, b), c);
    float s = exp2f(a - m) + exp2f(b - m) + exp2f(c - m);
    return m + log2f(s);
}

// ---------------- Kernel 1: row log-sum-exp + gather (register-resident) ----------------
__global__ __launch_bounds__(256)
void ctc_rowlse(const float* __restrict__ acts, const int* __restrict__ targets,
                float* __restrict__ lp) {
    const int B = 32, V = 8000, L = 100, RS = 104;
    const int bid = blockIdx.x;
    const int t = bid >> 5, b = bid & 31;
    const int tid = threadIdx.x;

    __shared__ float red[8];

    const float* rowp = acts + ((size_t)t * B + b) * V;
    const float4* g = (const float4*)rowp;

    // 2000 float4 / 256 threads: threads 0..207 take 8, rest 7 (guard j==7).
    float4 v[8];
    #pragma unroll
    for (int j = 0; j < 8; ++j) {
        int idx = tid + j * 256;
        if (j < 7 || tid < 208) v[j] = g[idx];
        else v[j] = make_float4(-3.0e38f, -3.0e38f, -3.0e38f, -3.0e38f);
    }

    float m = -3.0e38f;
    #pragma unroll
    for (int j = 0; j < 8; ++j)
        m = fmaxf(m, fmaxf(fmaxf(v[j].x, v[j].y), fmaxf(v[j].z, v[j].w)));
    #pragma unroll
    for (int o = 32; o > 0; o >>= 1) m = fmaxf(m, __shfl_xor(m, o));
    if ((tid & 63) == 0) red[tid >> 6] = m;
    __syncthreads();
    m = fmaxf(fmaxf(red[0], red[1]), fmaxf(red[2], red[3]));

    float s = 0.f;
    #pragma unroll
    for (int j = 0; j < 8; ++j) {
        s += exp2f((v[j].x - m) * LOG2E) + exp2f((v[j].y - m) * LOG2E)
           + exp2f((v[j].z - m) * LOG2E) + exp2f((v[j].w - m) * LOG2E);
    }
    #pragma unroll
    for (int o = 32; o > 0; o >>= 1) s += __shfl_xor(s, o);
    if ((tid & 63) == 0) red[4 + (tid >> 6)] = s;
    __syncthreads();
    s = red[4] + red[5] + red[6] + red[7];

    const float base = m * LOG2E + log2f(s);   // log2(sum exp), incl. max

    if (tid < 101) {
        int cls = (tid == 0) ? 0 : targets[b * L + tid - 1];
        // row is L2-hot (this block just streamed it); 101 scalar loads.
        lp[((size_t)b * 512 + t) * RS + tid] = rowp[cls] * LOG2E - base;
    }
}

// ---------------- Kernel 2: alpha recursion (1 wave / sample) ----------------
__global__ __launch_bounds__(64)
void ctc_alpha(const float* __restrict__ lp, const int* __restrict__ targets,
               const int* __restrict__ act_lens, const int* __restrict__ label_lens,
               float* __restrict__ partials) {
    const int T = 512, L = 100, RS = 104, CH = 32;
    const int b = blockIdx.x;
    const int l = threadIdx.x;

    __shared__ float4 buf[2][CH * RS / 4];   // 2 x 3328 floats = 26.6 KB
    __shared__ float afin[256];

    const int* tg = targets + b * L;

    // lane l owns states s0..s0+3; even states = blank (k=0), odd = labels
    const int s0 = 4 * l;
    const int i1 = 2 * l;        // label index of state s0+1
    const int i3 = 2 * l + 1;    // label index of state s0+3
    const bool v1 = (s0 + 1) <= 200;
    const bool v3 = (s0 + 3) <= 200;
    const int q1  = (i1 < L) ? i1 : (L - 1);
    const int q1m = (i1 >= 1) ? ((i1 - 1 < L) ? i1 - 1 : (L - 1)) : 0;
    const int q3  = (i3 < L) ? i3 : (L - 1);
    const int c1 = tg[q1], c1m = tg[q1m], c3 = tg[q3];
    const bool can1 = (i1 == 0) || (c1 != c1m);
    const bool can3 = (c3 != c1);
    const int k1 = v1 ? (1 + i1) : 0;
    const int k3 = v3 ? (1 + i3) : 0;
    const int act_len = act_lens[b];

    const float4* gsrc = (const float4*)(lp + (size_t)b * T * RS);

    // stage chunk 0
    float4 stg[13];
    #pragma unroll
    for (int i = 0; i < 13; ++i) stg[i] = gsrc[i * 64 + l];
    #pragma unroll
    for (int i = 0; i < 13; ++i) buf[0][i * 64 + l] = stg[i];
    __syncthreads();

    float a0 = NEGS, a1 = NEGS, a2 = NEGS, a3 = NEGS;
    {
        const float* row0 = (const float*)&buf[0][0];
        if (l == 0) { a0 = row0[0]; a1 = row0[1]; }
    }

    int gt = 1;
    for (int c = 0; c < 16; ++c) {
        if (c < 15) {   // issue next-chunk loads early (hide under compute)
            const float4* gn = gsrc + (size_t)(c + 1) * (CH * RS / 4);
            #pragma unroll
            for (int i = 0; i < 13; ++i) stg[i] = gn[i * 64 + l];
        }
        const float* rowbase = (const float*)&buf[c & 1][0];
        const int tstart = (c == 0) ? 1 : 0;
        for (int tt = tstart; tt < CH; ++tt, ++gt) {
            const float* row = rowbase + tt * RS;
            float lpB = row[0];
            float lq1 = v1 ? row[k1] : NEGS;
            float lq3 = v3 ? row[k3] : NEGS;
            float p3 = __shfl_up(a3, 1);           // alpha[s0-1] from lane l-1
            if (l == 0) p3 = NEGS;
            float na0 = lae2(a0, p3) + lpB;
            float na1 = lae3(a1, a0, can1 ? p3 : NEGS) + lq1;
            float na2 = lae2(a2, a1) + lpB;
            float na3 = lae3(a3, a2, can3 ? a1 : NEGS) + lq3;
            if (gt < act_len) { a0 = na0; a1 = na1; a2 = na2; a3 = na3; }
        }
        if (c < 15) {   // commit staged chunk, then make visible
            float4* dst = &buf[(c + 1) & 1][0];
            #pragma unroll
            for (int i = 0; i < 13; ++i) dst[i * 64 + l] = stg[i];
            __syncthreads();
        }
    }

    afin[4 * l + 0] = a0; afin[4 * l + 1] = a1;
    afin[4 * l + 2] = a2; afin[4 * l + 3] = a3;
    __syncthreads();
    if (l == 0) {
        int Lb = label_lens[b];
        int sl = 2 * Lb;
        float ll = lae2(afin[sl], afin[sl - 1]);   // log2 domain
        partials[b] = -ll * LN2;                   // back to natural log
    }
}

// ---------------- Kernel 3: final mean ----------------
__global__ __launch_bounds__(64)
void ctc_final(const float* __restrict__ partials, float* __restrict__ out) {
    int tid = threadIdx.x;
    float v = (tid < 32) ? partials[tid] : 0.f;
    #pragma unroll
    for (int o = 32; o > 0; o >>= 1) v += __shfl_xor(v, o);
    if (tid == 0) out[0] = v * (1.0f / 32.0f);
}

extern "C" void kernel_launch(void* const* d_in, const int* in_sizes, int n_in,
                              void* d_out, int out_size, void* d_ws, size_t ws_size,
                              hipStream_t stream) {
    const float* acts      = (const float*)d_in[0];
    const int*   targets   = (const int*)d_in[1];
    const int*   act_lens  = (const int*)d_in[2];
    const int*   label_lens= (const int*)d_in[3];

    float* lp       = (float*)d_ws;                                    // [32][512][104]
    float* partials = (float*)((char*)d_ws + (size_t)32 * 512 * 104 * sizeof(float));

    ctc_rowlse<<<16384, 256, 0, stream>>>(acts, targets, lp);
    ctc_alpha <<<32, 64, 0, stream>>>(lp, targets, act_lens, label_lens, partials);
    ctc_final <<<1, 64, 0, stream>>>(partials, (float*)d_out);
}